// Round 1
// baseline (1530.005 us; speedup 1.0000x reference)
//
#include <hip/hip_runtime.h>

// GCN 2-layer forward on gfx950.
// Sizes fixed by the problem: F=128 in-features, H=64 hidden, O=10 out.
static constexpr int F = 128;
static constexpr int H = 64;
static constexpr int O = 10;

__global__ __launch_bounds__(256) void k_init_deg(float* __restrict__ deg, int n) {
    int v = blockIdx.x * 256 + threadIdx.x;
    if (v < n) deg[v] = 1.0f;   // self-loop
}

__global__ __launch_bounds__(256) void k_count_deg(const int* __restrict__ dst,
                                                   float* __restrict__ deg, int e) {
    int i = blockIdx.x * 256 + threadIdx.x;
    if (i < e) atomicAdd(&deg[dst[i]], 1.0f);
}

__global__ __launch_bounds__(256) void k_dinv(const float* __restrict__ deg,
                                              float* __restrict__ dinv, int n) {
    int v = blockIdx.x * 256 + threadIdx.x;
    if (v < n) dinv[v] = rsqrtf(deg[v]);   // deg >= 1 always
}

// y[n][j]    = (x @ W1)[n][j] * dinv[n]         (pre-scaled by src-side dinv)
// agg1[n][j] = y[n][j] * dinv[n]                (self-loop contribution init)
// One wave = 64 j-lanes x 4 nodes (register blocking amortizes W1 loads 4x).
__global__ __launch_bounds__(256) void k_gemm1(
    const float* __restrict__ x, const float* __restrict__ W1,
    const float* __restrict__ dinv, float* __restrict__ y,
    float* __restrict__ agg1, int n_nodes) {
    const int j  = threadIdx.x & 63;
    const int wv = threadIdx.x >> 6;
    const int n0 = (blockIdx.x * 4 + wv) * 4;
    if (n0 >= n_nodes) return;
    if (n0 + 3 < n_nodes) {
        float a0 = 0.f, a1 = 0.f, a2 = 0.f, a3 = 0.f;
        const float* xr = x + (size_t)n0 * F;
        for (int k = 0; k < F; ++k) {
            float w = W1[k * H + j];           // coalesced 256B/wave, L1-resident
            a0 = fmaf(xr[k],         w, a0);   // x loads wave-uniform -> broadcast
            a1 = fmaf(xr[F + k],     w, a1);
            a2 = fmaf(xr[2 * F + k], w, a2);
            a3 = fmaf(xr[3 * F + k], w, a3);
        }
        float acc[4] = {a0, a1, a2, a3};
#pragma unroll
        for (int m = 0; m < 4; ++m) {
            float d  = dinv[n0 + m];
            float yv = acc[m] * d;
            y[(size_t)(n0 + m) * H + j]    = yv;
            agg1[(size_t)(n0 + m) * H + j] = yv * d;
        }
    } else {
        for (int m = 0; m < 4; ++m) {
            int n = n0 + m;
            if (n >= n_nodes) break;
            float a = 0.f;
            for (int k = 0; k < F; ++k) a = fmaf(x[(size_t)n * F + k], W1[k * H + j], a);
            float d = dinv[n];
            y[(size_t)n * H + j]    = a * d;
            agg1[(size_t)n * H + j] = a * d * d;
        }
    }
}

// agg1[dst][f] += y[src][f] * dinv[dst].  One wave per edge, lane = feature.
__global__ __launch_bounds__(256) void k_scatter1(
    const int* __restrict__ src, const int* __restrict__ dst,
    const float* __restrict__ dinv, const float* __restrict__ y,
    float* __restrict__ agg1, int n_edges) {
    int t = blockIdx.x * 256 + threadIdx.x;
    int e = t >> 6;
    int f = t & 63;
    if (e >= n_edges) return;
    int s = src[e], d = dst[e];
    float w = dinv[d];
    atomicAdd(&agg1[(size_t)d * H + f], y[(size_t)s * H + f] * w);
}

// h = relu(agg1 + b1); z[n][j] = (h @ W2)[n][j]*dinv[n]; out init = z*dinv + b2.
// One wave per node; 64-lane dot reduced by shuffle butterfly per output j.
__global__ __launch_bounds__(256) void k_layer2(
    const float* __restrict__ agg1, const float* __restrict__ b1,
    const float* __restrict__ W2, const float* __restrict__ b2,
    const float* __restrict__ dinv, float* __restrict__ z,
    float* __restrict__ out, int n_nodes) {
    const int l  = threadIdx.x & 63;
    const int wv = threadIdx.x >> 6;
    const int n  = blockIdx.x * 4 + wv;
    if (n >= n_nodes) return;
    float h = agg1[(size_t)n * H + l] + b1[l];
    h = fmaxf(h, 0.0f);
    const float d = dinv[n];
#pragma unroll
    for (int j = 0; j < O; ++j) {
        float v = h * W2[l * O + j];
#pragma unroll
        for (int off = 32; off > 0; off >>= 1) v += __shfl_xor(v, off, 64);
        if (l == j) {   // lane j writes feature j (v identical on all lanes)
            float zv = v * d;
            z[(size_t)n * O + j]   = zv;
            out[(size_t)n * O + j] = fmaf(zv, d, b2[j]);
        }
    }
}

// out[dst][j] += z[src][j] * dinv[dst].  One thread per edge, 10 features.
__global__ __launch_bounds__(256) void k_scatter2(
    const int* __restrict__ src, const int* __restrict__ dst,
    const float* __restrict__ dinv, const float* __restrict__ z,
    float* __restrict__ out, int n_edges) {
    int e = blockIdx.x * 256 + threadIdx.x;
    if (e >= n_edges) return;
    int s = src[e], d = dst[e];
    float w = dinv[d];
    const float* zr = z + (size_t)s * O;
    float* orow = out + (size_t)d * O;
#pragma unroll
    for (int j = 0; j < O; ++j) atomicAdd(&orow[j], zr[j] * w);
}

extern "C" void kernel_launch(void* const* d_in, const int* in_sizes, int n_in,
                              void* d_out, int out_size, void* d_ws, size_t ws_size,
                              hipStream_t stream) {
    const float* x  = (const float*)d_in[0];
    const int*   ei = (const int*)d_in[1];
    const float* W1 = (const float*)d_in[2];
    const float* b1 = (const float*)d_in[3];
    const float* W2 = (const float*)d_in[4];
    const float* b2 = (const float*)d_in[5];
    float* out = (float*)d_out;

    const int N = in_sizes[0] / F;   // 100000
    const int E = in_sizes[1] / 2;   // 1600000
    const int* src = ei;             // edge_index[0]
    const int* dst = ei + E;         // edge_index[1]

    // Workspace layout (floats): y[N*H] | agg1[N*H] | z[N*O] | deg[N] | dinv[N]
    float* ws   = (float*)d_ws;
    float* y    = ws;
    float* agg1 = y + (size_t)N * H;
    float* z    = agg1 + (size_t)N * H;
    float* deg  = z + (size_t)N * O;
    float* dinv = deg + N;

    const int nb_n = (N + 255) / 256;
    const int nb_e = (E + 255) / 256;

    k_init_deg<<<nb_n, 256, 0, stream>>>(deg, N);
    k_count_deg<<<nb_e, 256, 0, stream>>>(dst, deg, E);
    k_dinv<<<nb_n, 256, 0, stream>>>(deg, dinv, N);
    k_gemm1<<<(N + 15) / 16, 256, 0, stream>>>(x, W1, dinv, y, agg1, N);
    k_scatter1<<<(E * 64 + 255) / 256, 256, 0, stream>>>(src, dst, dinv, y, agg1, E);
    k_layer2<<<(N + 3) / 4, 256, 0, stream>>>(agg1, b1, W2, b2, dinv, z, out, N);
    k_scatter2<<<nb_e, 256, 0, stream>>>(src, dst, dinv, z, out, E);
}

// Round 2
// 580.870 us; speedup vs baseline: 2.6340x; 2.6340x over previous
//
#include <hip/hip_runtime.h>

// GCN 2-layer forward on gfx950 — CSR-gather formulation (no float atomics).
// F=128 in, H=64 hidden, O=10 out. N=100000 nodes, E=1600000 edges.
static constexpr int F = 128;
static constexpr int H = 64;
static constexpr int O = 10;

__global__ __launch_bounds__(256) void k_zero_int(int* __restrict__ p, int n) {
    int i = blockIdx.x * 256 + threadIdx.x;
    if (i < n) p[i] = 0;
}

__global__ __launch_bounds__(256) void k_count(const int* __restrict__ dst,
                                               int* __restrict__ cnt, int e) {
    int i = blockIdx.x * 256 + threadIdx.x;
    if (i < e) atomicAdd(&cnt[dst[i]], 1);
}

__global__ __launch_bounds__(256) void k_dinv(const int* __restrict__ cnt,
                                              float* __restrict__ dinv, int n) {
    int v = blockIdx.x * 256 + threadIdx.x;
    if (v < n) dinv[v] = rsqrtf((float)cnt[v] + 1.0f);   // +1 self-loop
}

// Exclusive scan of cnt[0..n] (n = N+1 entries) -> rowptr, per-256 block + bsum.
__global__ __launch_bounds__(256) void k_scan1(const int* __restrict__ cnt,
                                               int* __restrict__ rowptr,
                                               int* __restrict__ bsum, int n) {
    __shared__ int s[256];
    int t = threadIdx.x;
    int i = blockIdx.x * 256 + t;
    int v = (i < n) ? cnt[i] : 0;
    s[t] = v;
    __syncthreads();
    for (int off = 1; off < 256; off <<= 1) {
        int x = (t >= off) ? s[t - off] : 0;
        __syncthreads();
        s[t] += x;
        __syncthreads();
    }
    if (i < n) rowptr[i] = s[t] - v;          // exclusive
    if (t == 255) bsum[blockIdx.x] = s[255];  // block total
}

__global__ __launch_bounds__(512) void k_scan2(int* __restrict__ bsum, int nb) {
    __shared__ int s[512];
    int t = threadIdx.x;
    int v = (t < nb) ? bsum[t] : 0;
    s[t] = v;
    __syncthreads();
    for (int off = 1; off < 512; off <<= 1) {
        int x = (t >= off) ? s[t - off] : 0;
        __syncthreads();
        s[t] += x;
        __syncthreads();
    }
    if (t < nb) bsum[t] = s[t] - v;           // exclusive over block totals
}

__global__ __launch_bounds__(256) void k_scan3(int* __restrict__ rowptr,
                                               const int* __restrict__ bsum,
                                               int* __restrict__ cursor, int n) {
    int i = blockIdx.x * 256 + threadIdx.x;
    if (i < n) {
        int r = rowptr[i] + bsum[blockIdx.x];
        rowptr[i] = r;
        if (i < n - 1) cursor[i] = r;         // cursor over nodes only
    }
}

__global__ __launch_bounds__(256) void k_fill(const int* __restrict__ src,
                                              const int* __restrict__ dst,
                                              int* __restrict__ cursor,
                                              int* __restrict__ esrc, int e) {
    int i = blockIdx.x * 256 + threadIdx.x;
    if (i >= e) return;
    int pos = atomicAdd(&cursor[dst[i]], 1);
    esrc[pos] = src[i];
}

// y[n][j] = (x @ W1)[n][j] * dinv[n]   (pre-scaled by src-side dinv)
__global__ __launch_bounds__(256) void k_gemm1(
    const float* __restrict__ x, const float* __restrict__ W1,
    const float* __restrict__ dinv, float* __restrict__ y, int n_nodes) {
    const int j  = threadIdx.x & 63;
    const int wv = threadIdx.x >> 6;
    const int n0 = (blockIdx.x * 4 + wv) * 4;
    if (n0 >= n_nodes) return;
    if (n0 + 3 < n_nodes) {
        float a0 = 0.f, a1 = 0.f, a2 = 0.f, a3 = 0.f;
        const float* xr = x + (size_t)n0 * F;
        for (int k = 0; k < F; ++k) {
            float w = W1[k * H + j];
            a0 = fmaf(xr[k],         w, a0);
            a1 = fmaf(xr[F + k],     w, a1);
            a2 = fmaf(xr[2 * F + k], w, a2);
            a3 = fmaf(xr[3 * F + k], w, a3);
        }
        float acc[4] = {a0, a1, a2, a3};
#pragma unroll
        for (int m = 0; m < 4; ++m)
            y[(size_t)(n0 + m) * H + j] = acc[m] * dinv[n0 + m];
    } else {
        for (int m = 0; m < 4; ++m) {
            int n = n0 + m;
            if (n >= n_nodes) break;
            float a = 0.f;
            for (int k = 0; k < F; ++k) a = fmaf(x[(size_t)n * F + k], W1[k * H + j], a);
            y[(size_t)n * H + j] = a * dinv[n];
        }
    }
}

// h[n][j] = relu(dinv[n] * (y[n][j] + sum_{k in row} y[esrc[k]][j]) + b1[j])
// One wave per node, lane = feature. Edge indices are wave-uniform (s_load).
__global__ __launch_bounds__(256) void k_gather1(
    const float* __restrict__ y, const int* __restrict__ rowptr,
    const int* __restrict__ esrc, const float* __restrict__ dinv,
    const float* __restrict__ b1, float* __restrict__ h, int n_nodes) {
    const int j  = threadIdx.x & 63;
    const int n  = blockIdx.x * 4 + (threadIdx.x >> 6);
    if (n >= n_nodes) return;
    int beg = rowptr[n], end = rowptr[n + 1];
    float acc = y[(size_t)n * H + j];          // self-loop (one dinv already in y)
    int k = beg;
    for (; k + 3 < end; k += 4) {              // 4-deep to hide L2 latency
        int s0 = esrc[k], s1 = esrc[k + 1], s2 = esrc[k + 2], s3 = esrc[k + 3];
        float v0 = y[(size_t)s0 * H + j];
        float v1 = y[(size_t)s1 * H + j];
        float v2 = y[(size_t)s2 * H + j];
        float v3 = y[(size_t)s3 * H + j];
        acc += (v0 + v1) + (v2 + v3);
    }
    for (; k < end; ++k) acc += y[(size_t)esrc[k] * H + j];
    h[(size_t)n * H + j] = fmaxf(fmaf(dinv[n], acc, b1[j]), 0.0f);
}

// zs[n][j] = dinv[n] * (h[n] @ W2)[j]   — wave per node, shuffle reduction.
__global__ __launch_bounds__(256) void k_zs(
    const float* __restrict__ h, const float* __restrict__ W2,
    const float* __restrict__ dinv, float* __restrict__ zs, int n_nodes) {
    const int l = threadIdx.x & 63;
    const int n = blockIdx.x * 4 + (threadIdx.x >> 6);
    if (n >= n_nodes) return;
    float hv = h[(size_t)n * H + l];
    const float d = dinv[n];
#pragma unroll
    for (int j = 0; j < O; ++j) {
        float v = hv * W2[l * O + j];
#pragma unroll
        for (int off = 32; off > 0; off >>= 1) v += __shfl_xor(v, off, 64);
        if (l == j) zs[(size_t)n * O + j] = v * d;
    }
}

// out[n][j] = dinv[n] * (zs[n][j] + sum_{k in row} zs[esrc[k]][j]) + b2[j]
// 16 lanes per node (j<10 active), 16 nodes per block.
__global__ __launch_bounds__(256) void k_gather2(
    const float* __restrict__ zs, const int* __restrict__ rowptr,
    const int* __restrict__ esrc, const float* __restrict__ dinv,
    const float* __restrict__ b2, float* __restrict__ out, int n_nodes) {
    const int j = threadIdx.x & 15;
    const int n = blockIdx.x * 16 + (threadIdx.x >> 4);
    if (n >= n_nodes || j >= O) return;
    int beg = rowptr[n], end = rowptr[n + 1];
    float acc = zs[(size_t)n * O + j];         // self-loop
    int k = beg;
    for (; k + 1 < end; k += 2) {
        int s0 = esrc[k], s1 = esrc[k + 1];
        acc += zs[(size_t)s0 * O + j] + zs[(size_t)s1 * O + j];
    }
    for (; k < end; ++k) acc += zs[(size_t)esrc[k] * O + j];
    out[(size_t)n * O + j] = fmaf(dinv[n], acc, b2[j]);
}

extern "C" void kernel_launch(void* const* d_in, const int* in_sizes, int n_in,
                              void* d_out, int out_size, void* d_ws, size_t ws_size,
                              hipStream_t stream) {
    const float* x  = (const float*)d_in[0];
    const int*   ei = (const int*)d_in[1];
    const float* W1 = (const float*)d_in[2];
    const float* b1 = (const float*)d_in[3];
    const float* W2 = (const float*)d_in[4];
    const float* b2 = (const float*)d_in[5];
    float* out = (float*)d_out;

    const int N = in_sizes[0] / F;   // 100000
    const int E = in_sizes[1] / 2;   // 1600000
    const int* src = ei;
    const int* dst = ei + E;

    // Workspace: y[N*H] | h[N*H] | zs[N*O] | dinv[N] | cnt[N+1] | rowptr[N+1]
    //          | cursor[N] | bsum[512] | esrc[E]            (~63 MB total)
    float* y    = (float*)d_ws;
    float* h    = y + (size_t)N * H;
    float* zs   = h + (size_t)N * H;
    float* dinv = zs + (size_t)N * O;
    int* cnt    = (int*)(dinv + N);
    int* rowptr = cnt + (N + 1);
    int* cursor = rowptr + (N + 1);
    int* bsum   = cursor + N;
    int* esrc   = bsum + 512;

    const int nb_n  = (N + 255) / 256;
    const int nb_n1 = (N + 256) / 256;         // covers N+1 entries
    const int nb_e  = (E + 255) / 256;

    k_zero_int<<<nb_n1, 256, 0, stream>>>(cnt, N + 1);
    k_count<<<nb_e, 256, 0, stream>>>(dst, cnt, E);
    k_dinv<<<nb_n, 256, 0, stream>>>(cnt, dinv, N);
    k_scan1<<<nb_n1, 256, 0, stream>>>(cnt, rowptr, bsum, N + 1);
    k_scan2<<<1, 512, 0, stream>>>(bsum, nb_n1);           // nb_n1=391 <= 512
    k_scan3<<<nb_n1, 256, 0, stream>>>(rowptr, bsum, cursor, N + 1);
    k_fill<<<nb_e, 256, 0, stream>>>(src, dst, cursor, esrc, E);
    k_gemm1<<<(N + 15) / 16, 256, 0, stream>>>(x, W1, dinv, y, N);
    k_gather1<<<(N + 3) / 4, 256, 0, stream>>>(y, rowptr, esrc, dinv, b1, h, N);
    k_zs<<<(N + 3) / 4, 256, 0, stream>>>(h, W2, dinv, zs, N);
    k_gather2<<<(N + 15) / 16, 256, 0, stream>>>(zs, rowptr, esrc, dinv, b2, out, N);
}